// Round 6
// baseline (142.319 us; speedup 1.0000x reference)
//
#include <hip/hip_runtime.h>
#include <hip/hip_bf16.h>
#include <math.h>

#define Bn 8192
#define Dn 256
#define Pn 4096

using f16x8 = _Float16 __attribute__((ext_vector_type(8)));
using f16x4 = _Float16 __attribute__((ext_vector_type(4)));
using f32x16 = float __attribute__((ext_vector_type(16)));

// ------- normalize rows (fp32 -> f16) + per-chunk histogram + zero s_glob -------
// grid = (Bn+Pn)/4 blocks: rows [0,Bn) = embeddings, [Bn,Bn+Pn) = prototypes.
// Blocks 0..31 additionally build the 256-sample-chunk histograms of cid.
__global__ void norm_hist_kernel(const float* __restrict__ emb, const float* __restrict__ protos,
                                 const int* __restrict__ cid,
                                 _Float16* __restrict__ embn, _Float16* __restrict__ pron,
                                 float* __restrict__ s_glob, int* __restrict__ hist) {
    __shared__ int h[Pn];
    int gid  = blockIdx.x;
    bool do_hist = (gid < Bn / 256);
    if (do_hist)
        for (int c = threadIdx.x; c < Pn; c += 256) h[c] = 0;

    int row  = gid * 4 + (threadIdx.x >> 6);
    int lane = threadIdx.x & 63;
    const float* in;
    _Float16* out;
    int r;
    if (row < Bn) { in = emb;    out = embn; r = row; }
    else          { in = protos; out = pron; r = row - Bn; }
    const float4 v = reinterpret_cast<const float4*>(in + (size_t)r * Dn)[lane];
    float ss = v.x * v.x + v.y * v.y + v.z * v.z + v.w * v.w;
#pragma unroll
    for (int m = 1; m <= 32; m <<= 1) ss += __shfl_xor(ss, m);
    float scale = 1.0f / fmaxf(sqrtf(ss), 1e-12f);
    f16x4 o;
    o[0] = (_Float16)(v.x * scale);
    o[1] = (_Float16)(v.y * scale);
    o[2] = (_Float16)(v.z * scale);
    o[3] = (_Float16)(v.w * scale);
    reinterpret_cast<f16x4*>(out + (size_t)r * Dn)[lane] = o;

    if (gid < Bn / 1024) s_glob[gid * 256 + threadIdx.x] = 0.0f;

    if (do_hist) {
        __syncthreads();
        atomicAdd(&h[cid[gid * 256 + threadIdx.x]], 1);
        __syncthreads();
        for (int c = threadIdx.x; c < Pn; c += 256)
            hist[gid * Pn + c] = h[c];
    }
}

// ------- fused counts + per-chunk prefix + exclusive scan -> offs[Pn+1] -------
// one block, 1024 threads; thread t owns clusters 4t..4t+3
__global__ __launch_bounds__(1024)
void prefscan_kernel(const int* __restrict__ hist, int* __restrict__ pref,
                     int* __restrict__ offs) {
    __shared__ int wt[16];
    int t = threadIdx.x;
    int4 run = {0, 0, 0, 0};
    for (int ch = 0; ch < 32; ++ch) {
        int4 v = reinterpret_cast<const int4*>(hist + ch * Pn)[t];
        reinterpret_cast<int4*>(pref + ch * Pn)[t] = run;
        run.x += v.x; run.y += v.y; run.z += v.z; run.w += v.w;
    }
    int l1 = run.x, l2 = l1 + run.y, l3 = l2 + run.z;
    int tot = l3 + run.w;
    int v = tot;
#pragma unroll
    for (int d = 1; d < 64; d <<= 1) {
        int u = __shfl_up(v, d);
        if ((t & 63) >= d) v += u;
    }
    if ((t & 63) == 63) wt[t >> 6] = v;
    __syncthreads();
    int add = 0;
    for (int ww = 0; ww < (t >> 6); ++ww) add += wt[ww];
    int base = add + v - tot;   // exclusive prefix of this thread's 4-cluster group
    int4 o = {base, base + l1, base + l2, base + l3};
    reinterpret_cast<int4*>(offs)[t] = o;
    if (t == 0) offs[Pn] = Bn;
}

// ------- rank within cluster (deterministic, sample-index order) + CSR fill -------
__global__ void rankfill_kernel(const int* __restrict__ cid, const int* __restrict__ pref,
                                const int* __restrict__ offs, int* __restrict__ slist) {
    __shared__ int ids[256];
    int t = threadIdx.x, g = blockIdx.x;
    int i = g * 256 + t;
    int my = cid[i];
    ids[t] = my;
    __syncthreads();
    int r = pref[g * Pn + my];
    for (int j = 0; j < t; ++j) r += (ids[j] == my) ? 1 : 0;
    slist[offs[my] + r] = i;
}

// ---------------- GEMM + exp-sum + positive extraction ----------------
// Block: 128 rows x 256 cols, 4 waves (32 rows each), A fully in registers.
// B staged in LDS fragment-major via global_load_lds (per-lane permuted global
// source, linear LDS dest, lane-linear reads -> zero bank conflicts).
// s[row] = sum_{p != cid[row]} exp(sim-2);  pos_glob[row] = sim[row][cid[row]].
__global__ __launch_bounds__(256, 2)
void gemm_expsum_kernel(const _Float16* __restrict__ embn, const _Float16* __restrict__ pron,
                        const int* __restrict__ cid,
                        float* __restrict__ s_glob, float* __restrict__ pos_glob) {
    __shared__ _Float16 Bs[2][32 * Dn];   // 2 x 16 KB
    const int w    = threadIdx.x >> 6;
    const int lane = threadIdx.x & 63;
    const int lo   = lane & 31;
    const int hi   = lane >> 5;
    const int rbase = blockIdx.x * 128 + w * 32;
    const int cbase = blockIdx.y * 256;

    // A fragments: lane lo -> row rbase+lo, elems k = kk*16 + hi*8 + j
    const _Float16* ap = embn + (size_t)(rbase + lo) * Dn + hi * 8;
    f16x8 a[16];
#pragma unroll
    for (int kk = 0; kk < 16; ++kk)
        a[kk] = *reinterpret_cast<const f16x8*>(ap + kk * 16);

    // cid for the 16 output rows this lane owns (same rows for every col tile)
    int cidr[16];
#pragma unroll
    for (int r = 0; r < 16; ++r)
        cidr[r] = cid[rbase + (r & 3) + 8 * (r >> 2) + 4 * hi];

    float s[16];
#pragma unroll
    for (int r = 0; r < 16; ++r) s[r] = 0.0f;

    constexpr float K1 = 2.0f * 1.4426950408889634f;  // (1/TEMP) * log2(e)

    auto stage = [&](int sub, _Float16* buf) {
#pragma unroll
        for (int i = 0; i < 4; ++i) {
            int g = i * 4 + w;   // 16 granules per sub-chunk, 4 per wave
            const _Float16* gsrc =
                pron + (size_t)(cbase + sub * 32 + lo) * Dn + g * 16 + hi * 8;
            char* l = (char*)buf + (g << 10);   // wave-uniform base; +lane*16 implicit
            __builtin_amdgcn_global_load_lds(
                (const __attribute__((address_space(1))) unsigned int*)gsrc,
                (__attribute__((address_space(3))) unsigned int*)l, 16, 0, 0);
        }
    };

    stage(0, Bs[0]);
    __syncthreads();

    for (int sub = 0; sub < 8; ++sub) {
        const _Float16* cur = Bs[sub & 1];
        if (sub < 7) stage(sub + 1, Bs[(sub + 1) & 1]);   // async prefetch

        f32x16 acc;
#pragma unroll
        for (int r = 0; r < 16; ++r) acc[r] = 0.0f;
#pragma unroll
        for (int kk = 0; kk < 16; ++kk) {
            f16x8 b = *reinterpret_cast<const f16x8*>(
                (const char*)cur + (kk << 10) + (lane << 4));   // lane-linear
            acc = __builtin_amdgcn_mfma_f32_32x32x16_f16(a[kk], b, acc, 0, 0, 0);
        }
        int colv = cbase + sub * 32 + lo;
#pragma unroll
        for (int r = 0; r < 16; ++r) {
            float e = exp2f(fmaf(acc[r], K1, -K1));
            bool ispos = (cidr[r] == colv);
            s[r] += ispos ? 0.0f : e;     // exclude positive column exactly
            if (ispos)
                pos_glob[rbase + (r & 3) + 8 * (r >> 2) + 4 * hi] = acc[r] * 2.0f;
        }
        __syncthreads();   // prefetch landed + reads done before overwrite
    }

#pragma unroll
    for (int r = 0; r < 16; ++r) {
        float v = s[r];
        v += __shfl_xor(v, 1);
        v += __shfl_xor(v, 2);
        v += __shfl_xor(v, 4);
        v += __shfl_xor(v, 8);
        v += __shfl_xor(v, 16);
        if (lo == 0) {
            int row = rbase + (r & 3) + 8 * (r >> 2) + 4 * hi;
            atomicAdd(&s_glob[row], v);
        }
    }
}

// ------- EMA gather (one wave per cluster) + loss reduce on block 0 -------
// out[c] = M^cnt * p[c] + 0.1 * sum_j M^(cnt-1-j) * e_j ; loss = mean(log(s)+2-pos)
__global__ void update_loss_kernel(const float* __restrict__ protos, const float* __restrict__ emb,
                                   const int* __restrict__ offs, const int* __restrict__ slist,
                                   const float* __restrict__ s_glob, const float* __restrict__ pos_glob,
                                   float* __restrict__ out) {
    __shared__ float ws2[4];
    float* outp = out + 1;
    int w = threadIdx.x >> 6, lane = threadIdx.x & 63;
    int c = blockIdx.x * 4 + w;
    int off = offs[c], cnt = offs[c + 1] - off;
    float4 p = reinterpret_cast<const float4*>(protos + (size_t)c * Dn)[lane];
    float scale = __powf(0.9f, (float)cnt);
    float4 acc;
    acc.x = p.x * scale; acc.y = p.y * scale; acc.z = p.z * scale; acc.w = p.w * scale;
    for (int j = 0; j < cnt; ++j) {
        int i = slist[off + j];
        float wgt = 0.1f * __powf(0.9f, (float)(cnt - 1 - j));
        float4 e = reinterpret_cast<const float4*>(emb + (size_t)i * Dn)[lane];
        acc.x += wgt * e.x; acc.y += wgt * e.y; acc.z += wgt * e.z; acc.w += wgt * e.w;
    }
    reinterpret_cast<float4*>(outp + (size_t)c * Dn)[lane] = acc;

    if (blockIdx.x == 0) {
        float ssum = 0.0f;
        for (int i = threadIdx.x; i < Bn; i += 256)
            ssum += __logf(s_glob[i]) + 2.0f - pos_glob[i];
#pragma unroll
        for (int m = 1; m <= 32; m <<= 1) ssum += __shfl_xor(ssum, m);
        if ((threadIdx.x & 63) == 0) ws2[threadIdx.x >> 6] = ssum;
        __syncthreads();
        if (threadIdx.x == 0)
            out[0] = (ws2[0] + ws2[1] + ws2[2] + ws2[3]) * (1.0f / (float)Bn);
    }
}

extern "C" void kernel_launch(void* const* d_in, const int* in_sizes, int n_in,
                              void* d_out, int out_size, void* d_ws, size_t ws_size,
                              hipStream_t stream) {
    const float* emb    = (const float*)d_in[0];
    const float* protos = (const float*)d_in[1];
    const int*   cid    = (const int*)d_in[2];
    float* out = (float*)d_out;

    char* ws = (char*)d_ws;
    _Float16* embn = (_Float16*)ws;                                   // 4 MB
    _Float16* pron = (_Float16*)(ws + ((size_t)4 << 20));             // 2 MB
    float* s_glob  = (float*)(ws + ((size_t)6 << 20));                // 32 KB
    float* pos_g   = (float*)(ws + ((size_t)6 << 20) + 32768);        // 32 KB
    int*   offs    = (int*)(ws + ((size_t)6 << 20) + 65536);          // 16 KB + 4
    int*   slist   = (int*)(ws + ((size_t)6 << 20) + 98304);          // 32 KB
    int*   hist    = (int*)(ws + ((size_t)7 << 20));                  // 512 KB
    int*   pref    = (int*)(ws + ((size_t)7 << 20) + 524288);         // 512 KB

    norm_hist_kernel<<<(Bn + Pn) / 4, 256, 0, stream>>>(emb, protos, cid, embn, pron, s_glob, hist);
    prefscan_kernel<<<1, 1024, 0, stream>>>(hist, pref, offs);
    rankfill_kernel<<<Bn / 256, 256, 0, stream>>>(cid, pref, offs, slist);
    gemm_expsum_kernel<<<dim3(Bn / 128, Pn / 256), 256, 0, stream>>>(embn, pron, cid, s_glob, pos_g);
    update_loss_kernel<<<Pn / 4, 256, 0, stream>>>(protos, emb, offs, slist, s_glob, pos_g, out);
}